// Round 20
// baseline (127.630 us; speedup 1.0000x reference)
//
#include <hip/hip_runtime.h>
#include <hip/hip_bf16.h>
#include <math.h>

#define FEATN 12544
#define NIMG 1024
#define PLANE2 258   // half-image h1s plane pitch in dwords (258%32=2 -> spreads banks)

typedef __attribute__((ext_vector_type(8))) short short8;
typedef __attribute__((ext_vector_type(4))) float f32x4;

// ---- ws byte offsets (all sizes in BYTES; bf16 regions are 2 B/elem) ----
#define OFF_W1F   0            //  2048 bf16  =     4096 B   conv1 B-frag table
#define OFF_W2F   6144         //  32768 bf16 =    65536 B   conv2 B-frag table
#define OFF_WBBF  71680        //  1605632 bf16 = 3211264 B  gemm_u B-frag table
#define OFF_FEATB 62265344     //  1024*12544 bf16 = 25690112 B
#define OFF_U     87955456     //  131072 f32 = 524288 B   (layout [t][c][b])
#define OFF_PART  88479744     //  28*131072 f32 = 14680064 B
#define OFF_WHF   103163904    //  8192 bf16 = 16384 B   rnn Wh B-frag table
#define OFF_WGF   103180288    //  32768 bf16 = 65536 B  rnn [ff1|ff2|ta+tb|0] B-frag table (k' relabeled)
#define WS_BYTES  103245824

__device__ __forceinline__ unsigned short f2bf(float v) {
    union { float f; unsigned int u; } c; c.f = v;
    unsigned int r = c.u + 0x7FFFu + ((c.u >> 16) & 1u);   // RNE
    return (unsigned short)(r >> 16);
}
// round-half-up bf16 (2 ops); differs from RNE only at exact ties
__device__ __forceinline__ unsigned short f2bf_rhu(float v) {
    union { float f; unsigned int u; } c; c.f = v;
    return (unsigned short)((c.u + 0x8000u) >> 16);
}
// pack 2 f32 -> dword of 2 bf16 (round-half-up), lo in bits 0-15
__device__ __forceinline__ unsigned int pack2bf_rhu(float lo, float hi) {
    union { float f; unsigned int u; } a, b; a.f = lo; b.f = hi;
    return ((a.u + 0x8000u) >> 16) | ((b.u + 0x8000u) & 0xFFFF0000u);
}

// clamp-free activations: exp2 saturates (inf / 0) so asymptotes are exact.
__device__ __forceinline__ float lecun_tanh_fast(float x) {   // 1.7159*tanh(0.666*x)
    float e = __builtin_amdgcn_exp2f(1.9216698f * x);
    return 1.7159f - 3.4318f * __builtin_amdgcn_rcpf(e + 1.f);
}
__device__ __forceinline__ float tanh_fast(float x) {         // 1 - 2/(e^{2x}+1)
    float e = __builtin_amdgcn_exp2f(2.8853901f * x);
    return 1.f - 2.f * __builtin_amdgcn_rcpf(e + 1.f);
}
__device__ __forceinline__ float sigmoid_fast(float x) {      // 1/(1+e^{-x})
    float e = __builtin_amdgcn_exp2f(-1.4426950f * x);
    return __builtin_amdgcn_rcpf(1.f + e);
}

// ---------------- merged weight-prep kernel (R17-measured version) ----------------
__global__ __launch_bounds__(256) void prep_all(const float* __restrict__ w1, const float* __restrict__ w2,
                         const float* __restrict__ Wbb,
                         const float* __restrict__ Wff1, const float* __restrict__ Wff2,
                         const float* __restrict__ Wta,  const float* __restrict__ Wtb,
                         unsigned short* __restrict__ w1f, unsigned short* __restrict__ w2f,
                         unsigned short* __restrict__ wbbf,
                         unsigned short* __restrict__ whf, unsigned short* __restrict__ wgf) {
    int bid = blockIdx.x, tid = threadIdx.x;
    if (bid < 6272) {                       // Wbb(feat) -> wbbf, 1605632
        int i = bid * 256 + tid;
        int j = i & 7, lane = (i >> 3) & 63, nt = (i >> 9) & 7, kstep = i >> 12;
        int f = kstep * 32 + (lane >> 4) * 8 + j;
        int col = nt * 16 + (lane & 15);
        wbbf[i] = f2bf(Wbb[(size_t)f * 128 + col]);
    } else if (bid < 6400) {                // w2 -> w2f, 32768
        int i = (bid - 6272) * 256 + tid;
        int j = i & 7, lane = (i >> 3) & 63, kstep = (i >> 9) & 15, nt = i >> 13;
        int oc = nt * 16 + (lane & 15);
        int ic = 2 * kstep + (j >> 2);
        int ky = lane >> 4, kx = j & 3;
        w2f[i] = f2bf(w2[oc * 512 + ic * 16 + ky * 4 + kx]);
    } else if (bid < 6528) {                // gates -> wgf; m=2 holds Wta+Wtb, m=3 zero
        // k' relabeling (matches rnn packed-z layout): korig = kstep*32 + (j&1)*16 + g'*4 + (j>>1)
        int i = (bid - 6400) * 256 + tid;
        int j = i & 7, lane = (i >> 3) & 63, nt = (i >> 9) & 15, kstep = (i >> 13) & 3;
        int gq = (lane >> 4) & 3;
        int k = kstep * 32 + (j & 1) * 16 + gq * 4 + (j >> 1);
        int m = nt >> 2;
        int c = (nt & 3) * 16 + (lane & 15);
        float v;
        if (m == 0)      v = Wff1[k * 64 + c];
        else if (m == 1) v = Wff2[k * 64 + c];
        else if (m == 2) v = Wta[k * 64 + c] + Wtb[k * 64 + c];
        else             v = 0.f;
        wgf[i] = f2bf(v);
    } else if (bid < 6560) {                // Wh -> whf, 8192
        int i = (bid - 6528) * 256 + tid;
        int j = i & 7, lane = (i >> 3) & 63, nt = (i >> 9) & 7, kstep = (i >> 12) & 1;
        int k = kstep * 32 + ((lane >> 4) & 3) * 8 + j;
        int col = nt * 16 + (lane & 15);
        whf[i] = f2bf(Wbb[(size_t)(FEATN + k) * 128 + col]);
    } else {                                // w1 -> w1f, 2048
        int i = (bid - 6560) * 256 + tid;
        if (i >= 2048) return;
        int j = i & 7, lane = (i >> 3) & 63, nt = (i >> 9) & 1, kstep = (i >> 10) & 1;
        int oc = nt * 16 + (lane & 15);
        int ky = (lane >> 4) & 3, kx = j & 3;
        float v;
        if (kstep == 0) { int ic = j >> 2; v = w1[oc * 48 + ic * 16 + ky * 4 + kx]; }
        else            { v = (j >> 2) == 0 ? w1[oc * 48 + 32 + ky * 4 + kx] : 0.f; }
        w1f[i] = f2bf(v);
    }
}

// ---------------- fused conv1+conv2, HALF-IMAGE blocks, bf16 MFMA ----------------
// grid 2048: block = (img, h) with h = y-half. h1s tile = 32 ic x 16 y x 32 pitch
// = 33 KB -> 4 blocks/CU (32 waves/CU). conv1 recomputes the 2-row overlap.
// Part A: 30 mtiles over 8 waves (4 iters). Part B: 7 mtiles (1/wave).
__global__ __launch_bounds__(512) void fused_conv(const float* __restrict__ x,
                                                  const float* __restrict__ b1,
                                                  const unsigned short* __restrict__ w1f,
                                                  const float* __restrict__ b2,
                                                  const unsigned short* __restrict__ w2f,
                                                  unsigned short* __restrict__ featb) {
    __shared__ unsigned short h1s[32 * 2 * PLANE2];   // 33024 B
    int img = blockIdx.x >> 1;
    int h   = blockIdx.x & 1;
    int tid = threadIdx.x;
    int lane = tid & 63, wid = tid >> 6;               // wid 0..7
    int rowl = lane & 15, g = lane >> 4;
    const float* xg = x + (size_t)img * 11532;

    // ---- Part A: conv1 -> h1s rows ly=0..15 (global h1 y = h*14 + ly) ----
    {
        short8 bfr[2][2];
        #pragma unroll
        for (int ks = 0; ks < 2; ++ks)
            #pragma unroll
            for (int nt = 0; nt < 2; ++nt)
                bfr[ks][nt] = *(const short8*)(w1f + (((ks * 2 + nt) * 64 + lane) << 3));
        float bias0 = b1[rowl], bias1 = b1[16 + rowl];

        #pragma unroll
        for (int i = 0; i < 4; ++i) {
            int mtile = wid + 8 * i;
            if (mtile >= 30) break;
            int m = mtile * 16 + rowl; if (m > 479) m = 479;
            int ly = m / 30, ox = m - ly * 30;
            int yx = 28 * h + 2 * ly + g;              // x row
            const float* xb = xg + yx * 62 + 2 * ox;
            union { unsigned int u[4]; short8 s; } af0, af1;
            #pragma unroll
            for (int c = 0; c < 2; ++c) {
                float2 p0 = *(const float2*)(xb + c * 3844);
                float2 p1 = *(const float2*)(xb + c * 3844 + 2);
                af0.u[c * 2]     = pack2bf_rhu(p0.x, p0.y);
                af0.u[c * 2 + 1] = pack2bf_rhu(p1.x, p1.y);
            }
            {
                float2 q0 = *(const float2*)(xb + 7688);
                float2 q1 = *(const float2*)(xb + 7690);
                af1.u[0] = pack2bf_rhu(q0.x, q0.y);
                af1.u[1] = pack2bf_rhu(q1.x, q1.y);
                af1.u[2] = 0; af1.u[3] = 0;
            }
            f32x4 acc0 = (f32x4){0.f, 0.f, 0.f, 0.f};
            f32x4 acc1 = (f32x4){0.f, 0.f, 0.f, 0.f};
            acc0 = __builtin_amdgcn_mfma_f32_16x16x32_bf16(af0.s, bfr[0][0], acc0, 0, 0, 0);
            acc0 = __builtin_amdgcn_mfma_f32_16x16x32_bf16(af1.s, bfr[1][0], acc0, 0, 0, 0);
            acc1 = __builtin_amdgcn_mfma_f32_16x16x32_bf16(af0.s, bfr[0][1], acc1, 0, 0, 0);
            acc1 = __builtin_amdgcn_mfma_f32_16x16x32_bf16(af1.s, bfr[1][1], acc1, 0, 0, 0);
            // epilogue: bias+relu+bf16 -> h1s[oc][ly][ox]
            int sp0 = mtile * 16 + g * 4;
            int ly0 = sp0 / 30, ox0 = sp0 - ly0 * 30;
            #pragma unroll
            for (int nt = 0; nt < 2; ++nt) {
                f32x4 a = nt ? acc1 : acc0;
                int oc = nt * 16 + rowl;
                float bias = nt ? bias1 : bias0;
                int pbase = oc * (2 * PLANE2);          // shorts
                #pragma unroll
                for (int r = 0; r < 4; ++r) {
                    if (sp0 + r > 479) break;
                    int oxr = ox0 + r, lyr = ly0;
                    if (oxr >= 30) { oxr -= 30; ++lyr; }
                    h1s[pbase + lyr * 32 + oxr] = f2bf_rhu(fmaxf(a[r] + bias, 0.f));
                }
            }
        }
    }
    __syncthreads();

    // ---- Part B: conv2 for oy = h*7 + (0..6) -> featb (7 mtiles over sp_local 0..97) ----
    if (wid < 7) {
        int mtile = wid;
        f32x4 acc[4];
        #pragma unroll
        for (int nt = 0; nt < 4; ++nt) acc[nt] = (f32x4){0.f, 0.f, 0.f, 0.f};

        int m = mtile * 16 + rowl; if (m > 97) m = 97;
        int oyl = m / 14, ox = m - oyl * 14;
        int dof0 = (2 * oyl + g) * 16 + ox;            // dword offset within ic plane
        const unsigned int* lds32 = (const unsigned int*)h1s;

        #pragma unroll 4
        for (int kstep = 0; kstep < 16; ++kstep) {
            short8 bfr[4];
            #pragma unroll
            for (int nt = 0; nt < 4; ++nt)
                bfr[nt] = *(const short8*)(w2f + (((nt * 16 + kstep) * 64 + lane) << 3));
            int dof = kstep * 2 * PLANE2 + dof0;
            union { unsigned int u[4]; short8 s; } af;
            af.u[0] = lds32[dof];
            af.u[1] = lds32[dof + 1];
            af.u[2] = lds32[dof + PLANE2];
            af.u[3] = lds32[dof + PLANE2 + 1];
            #pragma unroll
            for (int nt = 0; nt < 4; ++nt)
                acc[nt] = __builtin_amdgcn_mfma_f32_16x16x32_bf16(af.s, bfr[nt], acc[nt], 0, 0, 0);
        }
        int spl0 = mtile * 16 + g * 4;                 // local sp (0..97)
        int spg0 = h * 98 + spl0;                      // global sp
        #pragma unroll
        for (int nt = 0; nt < 4; ++nt) {
            int oc = nt * 16 + rowl;
            float bias = b2[oc];
            unsigned short pk[4];
            #pragma unroll
            for (int r = 0; r < 4; ++r)
                pk[r] = f2bf_rhu(fmaxf(acc[nt][r] + bias, 0.f));
            unsigned short* dstp = featb + (size_t)img * 12544 + oc * 196 + spg0;
            if (spl0 + 3 <= 97) {                      // 4B-aligned paired stores (spg0 even)
                ((unsigned int*)dstp)[0] = (unsigned int)pk[0] | ((unsigned int)pk[1] << 16);
                ((unsigned int*)dstp)[1] = (unsigned int)pk[2] | ((unsigned int)pk[3] << 16);
            } else {
                #pragma unroll
                for (int r = 0; r < 4; ++r) if (spl0 + r <= 97) dstp[r] = pk[r];
            }
        }
    }
}

// ---------------- u = feat @ W_in : bf16 MFMA, split-K=28 (R14-measured config) ----------------
__global__ __launch_bounds__(256) void gemm_u_mfma(const unsigned short* __restrict__ featb,
                                                   const unsigned short* __restrict__ Wbbf,
                                                   float* __restrict__ part) {
    int tid = threadIdx.x, lane = tid & 63, wid = tid >> 6;
    int rowl = lane & 15, g = lane >> 4;
    int m0 = blockIdx.x * 64 + wid * 16;
    int ks0 = blockIdx.y * 14;
    f32x4 acc[8];
    #pragma unroll
    for (int nt = 0; nt < 8; ++nt) acc[nt] = (f32x4){0.f, 0.f, 0.f, 0.f};
    const unsigned short* arow = featb + (size_t)(m0 + rowl) * FEATN + g * 8;
    #pragma unroll 2
    for (int kk = 0; kk < 14; ++kk) {
        int kstep = ks0 + kk;
        short8 afr = *(const short8*)(arow + kstep * 32);
        #pragma unroll
        for (int nt = 0; nt < 8; ++nt) {
            short8 bfr = *(const short8*)(Wbbf + ((((size_t)kstep * 8 + nt) * 64 + lane) << 3));
            acc[nt] = __builtin_amdgcn_mfma_f32_16x16x32_bf16(afr, bfr, acc[nt], 0, 0, 0);
        }
    }
    float* pg = part + (size_t)blockIdx.y * 131072;
    #pragma unroll
    for (int nt = 0; nt < 8; ++nt)
        #pragma unroll
        for (int r = 0; r < 4; ++r)
            pg[(m0 + g * 4 + r) * 128 + nt * 16 + rowl] = acc[nt][r];
}

// reduce 28 splits; write u transposed to [t][c][b] (4 scalar stores)
__global__ void reduce_u(const float4* __restrict__ part4, const float* __restrict__ bbb,
                         float* __restrict__ u) {
    int o = blockIdx.x * 256 + threadIdx.x;   // 32768 float4s over c
    int c4 = o & 31, b = (o >> 5) & 15, t = o >> 9;
    int m = b * 64 + t;
    float4 s = *(const float4*)(bbb + c4 * 4);
    #pragma unroll
    for (int ks = 0; ks < 28; ++ks) {
        float4 p = part4[(size_t)ks * 32768 + m * 32 + c4];
        s.x += p.x; s.y += p.y; s.z += p.z; s.w += p.w;
    }
    int cb = c4 * 4;
    u[((size_t)t * 128 + cb + 0) * 16 + b] = s.x;
    u[((size_t)t * 128 + cb + 1) * 16 + b] = s.y;
    u[((size_t)t * 128 + cb + 2) * 16 + b] = s.z;
    u[((size_t)t * 128 + cb + 3) * 16 + b] = s.w;
}

// ---------------- liquid RNN scan + fused head: 1 block, 4 waves, single-bf16 state ----------------
__global__ __launch_bounds__(256, 1) void rnn_mfma(const float* __restrict__ u,
                                                   const unsigned short* __restrict__ whf,
                                                   const unsigned short* __restrict__ wgf,
                                                   const float* __restrict__ bff1,
                                                   const float* __restrict__ bff2,
                                                   const float* __restrict__ bta,
                                                   const float* __restrict__ btb,
                                                   const float* __restrict__ Wout,
                                                   const float* __restrict__ bout,
                                                   float* __restrict__ out) {
    __shared__ unsigned short hidA[16 * 64];    // [row][k0..63]
    __shared__ unsigned short zA[16 * 128];     // [row][k' 0..127] (reused as f32 hid for head)
    int tid = threadIdx.x, lane = tid & 63, w = tid >> 6;
    int rowl = lane & 15, g = lane >> 4;

    for (int idx = tid; idx < 1024; idx += 256) hidA[idx] = 0;

    // B-fragments -> registers (once)
    short8 wh_r[2][2];   // [kstep][ntl], nt_abs = 2w + ntl
    #pragma unroll
    for (int ks = 0; ks < 2; ++ks)
        #pragma unroll
        for (int ntl = 0; ntl < 2; ++ntl)
            wh_r[ks][ntl] = *(const short8*)(whf + (((ks * 8 + 2 * w + ntl) * 64 + lane) << 3));
    short8 wg_r[3][4];   // [m][kstep], nt_abs = 4m + w  (m=2 holds Wta+Wtb)
    #pragma unroll
    for (int m = 0; m < 3; ++m)
        #pragma unroll
        for (int ks = 0; ks < 4; ++ks)
            wg_r[m][ks] = *(const short8*)(wgf + (((ks * 16 + 4 * m + w) * 64 + lane) << 3));

    int cc = w * 16 + rowl;                   // this lane's phase-2 column
    float bias1 = bff1[cc], bias2 = bff2[cc], biast = bta[cc] + btb[cc];

    // u [t][c][b] pointers: 2 float4 loads per step (b = g*4..g*4+3)
    const float* ub0 = u + ((size_t)(2 * w) * 16 + rowl) * 16 + g * 4;        // c0 slice
    const float* ub1 = u + ((size_t)(2 * w + 1) * 16 + rowl) * 16 + g * 4;    // c1 slice
    f32x4 upf[2];
    {
        float4 v0 = *(const float4*)ub0;
        float4 v1 = *(const float4*)ub1;
        upf[0] = (f32x4){v0.x, v0.y, v0.z, v0.w};
        upf[1] = (f32x4){v1.x, v1.y, v1.z, v1.w};
    }
    __syncthreads();

    float hidv[4];
    #pragma unroll 1
    for (int t = 0; t < 64; ++t) {
        // ---- Phase 1: z = lecun_tanh(u_t + hid @ Wh) ----
        short8 ah[2];
        #pragma unroll
        for (int ks = 0; ks < 2; ++ks) {
            int byte = (rowl * 128 + ks * 64 + g * 16) ^ ((rowl & 7) << 4);
            ah[ks] = *(const short8*)((const char*)hidA + byte);
        }
        f32x4 zacc[2];
        #pragma unroll
        for (int ntl = 0; ntl < 2; ++ntl) {
            zacc[ntl] = upf[ntl];
            #pragma unroll
            for (int ks = 0; ks < 2; ++ks)
                zacc[ntl] = __builtin_amdgcn_mfma_f32_16x16x32_bf16(ah[ks], wh_r[ks][ntl], zacc[ntl], 0, 0, 0);
        }
        // prefetch u for t+1 (overlaps rest of step)
        if (t < 63) {
            float4 v0 = *(const float4*)(ub0 + (size_t)(t + 1) * 2048);
            float4 v1 = *(const float4*)(ub1 + (size_t)(t + 1) * 2048);
            upf[0] = (f32x4){v0.x, v0.y, v0.z, v0.w};
            upf[1] = (f32x4){v1.x, v1.y, v1.z, v1.w};
        }
        // tanh + packed z write: k' = w*32 + rowl*2 + ntl -> one b32 per row
        #pragma unroll
        for (int r = 0; r < 4; ++r) {
            float z0 = lecun_tanh_fast(zacc[0][r]);
            float z1 = lecun_tanh_fast(zacc[1][r]);
            int row = g * 4 + r;
            int byte = (row * 256 + w * 64 + rowl * 4) ^ ((row & 7) << 4);
            *(unsigned int*)((char*)zA + byte) = pack2bf_rhu(z0, z1);
        }
        __syncthreads();
        // ---- Phase 2: [ff1|ff2|t] = z @ Wg ----
        short8 zfr[4];
        #pragma unroll
        for (int ks = 0; ks < 4; ++ks) {
            int byte = (rowl * 256 + ks * 64 + g * 16) ^ ((rowl & 7) << 4);
            zfr[ks] = *(const short8*)((const char*)zA + byte);
        }
        f32x4 facc[3];
        facc[0] = (f32x4){bias1, bias1, bias1, bias1};
        facc[1] = (f32x4){bias2, bias2, bias2, bias2};
        facc[2] = (f32x4){biast, biast, biast, biast};
        #pragma unroll
        for (int m = 0; m < 3; ++m)
            #pragma unroll
            for (int ks = 0; ks < 4; ++ks)
                facc[m] = __builtin_amdgcn_mfma_f32_16x16x32_bf16(zfr[ks], wg_r[m][ks], facc[m], 0, 0, 0);
        // activations + hid write (bf16)
        #pragma unroll
        for (int r = 0; r < 4; ++r) {
            float ff1 = tanh_fast(facc[0][r]);
            float ff2 = tanh_fast(facc[1][r]);
            float tt  = sigmoid_fast(facc[2][r]);
            float hv  = ff1 + tt * (ff2 - ff1);
            hidv[r] = hv;
            int row = g * 4 + r;
            int byte = (row * 128 + cc * 2) ^ ((row & 7) << 4);
            *(unsigned short*)((char*)hidA + byte) = f2bf_rhu(hv);
        }
        __syncthreads();
    }

    // ---- fused head: out[b][a] = hid[b] . Wout[:,a] + bout[a] ----
    float* hf = (float*)zA;                    // 16*64 f32 = 4096 B
    #pragma unroll
    for (int r = 0; r < 4; ++r) hf[(g * 4 + r) * 64 + cc] = hidv[r];
    __syncthreads();
    if (tid < 128) {
        int b = tid >> 3, a = tid & 7;
        float s = bout[a];
        #pragma unroll
        for (int j = 0; j < 64; ++j) s += hf[b * 64 + j] * Wout[j * 8 + a];
        out[tid] = s;
    }
}

extern "C" void kernel_launch(void* const* d_in, const int* in_sizes, int n_in,
                              void* d_out, int out_size, void* d_ws, size_t ws_size,
                              hipStream_t stream) {
    const float* x    = (const float*)d_in[0];
    const float* w1   = (const float*)d_in[1];
    const float* b1   = (const float*)d_in[2];
    const float* w2   = (const float*)d_in[3];
    const float* b2   = (const float*)d_in[4];
    const float* Wbb  = (const float*)d_in[5];
    const float* bbb  = (const float*)d_in[6];
    const float* Wff1 = (const float*)d_in[7];
    const float* bff1 = (const float*)d_in[8];
    const float* Wff2 = (const float*)d_in[9];
    const float* bff2 = (const float*)d_in[10];
    const float* Wta  = (const float*)d_in[11];
    const float* bta  = (const float*)d_in[12];
    const float* Wtb  = (const float*)d_in[13];
    const float* btb  = (const float*)d_in[14];
    const float* Wout = (const float*)d_in[15];
    const float* bout = (const float*)d_in[16];

    if (ws_size < (size_t)WS_BYTES) return;

    char* wsb = (char*)d_ws;
    unsigned short* w1f   = (unsigned short*)(wsb + OFF_W1F);
    unsigned short* w2f   = (unsigned short*)(wsb + OFF_W2F);
    unsigned short* wbbf  = (unsigned short*)(wsb + OFF_WBBF);
    unsigned short* featb = (unsigned short*)(wsb + OFF_FEATB);
    float*          u     = (float*)(wsb + OFF_U);
    float*          part  = (float*)(wsb + OFF_PART);
    unsigned short* whf   = (unsigned short*)(wsb + OFF_WHF);
    unsigned short* wgf   = (unsigned short*)(wsb + OFF_WGF);

    prep_all<<<6568, 256, 0, stream>>>(w1, w2, Wbb, Wff1, Wff2, Wta, Wtb,
                                       w1f, w2f, wbbf, whf, wgf);
    fused_conv<<<2048, 512, 0, stream>>>(x, b1, w1f, b2, w2f, featb);
    gemm_u_mfma<<<dim3(16, 28), 256, 0, stream>>>(featb, wbbf, part);
    reduce_u<<<128, 256, 0, stream>>>((const float4*)part, bbb, u);
    rnn_mfma<<<1, 256, 0, stream>>>(u, whf, wgf, bff1, bff2, bta, btb, Wout, bout, (float*)d_out);
}

// Round 21
// 115.241 us; speedup vs baseline: 1.1075x; 1.1075x over previous
//
#include <hip/hip_runtime.h>
#include <hip/hip_bf16.h>
#include <math.h>

#define FEATN 12544
#define NIMG 1024
#define PLANEP 482   // h1s per-ic plane pitch in dwords (482%32=2 -> spreads banks)

typedef __attribute__((ext_vector_type(8))) short short8;
typedef __attribute__((ext_vector_type(4))) float f32x4;

// ---- ws byte offsets (all sizes in BYTES; bf16 regions are 2 B/elem) ----
#define OFF_W1F   0            //  2048 bf16  =     4096 B   conv1 B-frag table
#define OFF_W2F   6144         //  32768 bf16 =    65536 B   conv2 B-frag table
#define OFF_WBBF  71680        //  1605632 bf16 = 3211264 B  gemm_u B-frag table
#define OFF_FEATB 62265344     //  1024*12544 bf16 = 25690112 B
#define OFF_U     87955456     //  131072 f32 = 524288 B   (layout [t][c][b])
#define OFF_PART  88479744     //  28*131072 f32 = 14680064 B
#define OFF_WHF   103163904    //  8192 bf16 = 16384 B   rnn Wh B-frag table
#define OFF_WGF   103180288    //  32768 bf16 = 65536 B  rnn [ff1|ff2|ta+tb|0] B-frag table (k' relabeled)
#define WS_BYTES  103245824

__device__ __forceinline__ unsigned short f2bf(float v) {
    union { float f; unsigned int u; } c; c.f = v;
    unsigned int r = c.u + 0x7FFFu + ((c.u >> 16) & 1u);   // RNE
    return (unsigned short)(r >> 16);
}
// round-half-up bf16 (2 ops); differs from RNE only at exact ties
__device__ __forceinline__ unsigned short f2bf_rhu(float v) {
    union { float f; unsigned int u; } c; c.f = v;
    return (unsigned short)((c.u + 0x8000u) >> 16);
}
// pack 2 f32 -> dword of 2 bf16 (round-half-up), lo in bits 0-15
__device__ __forceinline__ unsigned int pack2bf_rhu(float lo, float hi) {
    union { float f; unsigned int u; } a, b; a.f = lo; b.f = hi;
    return ((a.u + 0x8000u) >> 16) | ((b.u + 0x8000u) & 0xFFFF0000u);
}

// clamp-free activations: exp2 saturates (inf / 0) so asymptotes are exact.
__device__ __forceinline__ float lecun_tanh_fast(float x) {   // 1.7159*tanh(0.666*x)
    float e = __builtin_amdgcn_exp2f(1.9216698f * x);
    return 1.7159f - 3.4318f * __builtin_amdgcn_rcpf(e + 1.f);
}
__device__ __forceinline__ float tanh_fast(float x) {         // 1 - 2/(e^{2x}+1)
    float e = __builtin_amdgcn_exp2f(2.8853901f * x);
    return 1.f - 2.f * __builtin_amdgcn_rcpf(e + 1.f);
}
__device__ __forceinline__ float sigmoid_fast(float x) {      // 1/(1+e^{-x})
    float e = __builtin_amdgcn_exp2f(-1.4426950f * x);
    return __builtin_amdgcn_rcpf(1.f + e);
}

// ---------------- merged weight-prep kernel (5-in-1) ----------------
__global__ __launch_bounds__(256) void prep_all(const float* __restrict__ w1, const float* __restrict__ w2,
                         const float* __restrict__ Wbb,
                         const float* __restrict__ Wff1, const float* __restrict__ Wff2,
                         const float* __restrict__ Wta,  const float* __restrict__ Wtb,
                         unsigned short* __restrict__ w1f, unsigned short* __restrict__ w2f,
                         unsigned short* __restrict__ wbbf,
                         unsigned short* __restrict__ whf, unsigned short* __restrict__ wgf) {
    int bid = blockIdx.x, tid = threadIdx.x;
    if (bid < 6272) {                       // Wbb(feat) -> wbbf, 1605632
        int i = bid * 256 + tid;
        int j = i & 7, lane = (i >> 3) & 63, nt = (i >> 9) & 7, kstep = i >> 12;
        int f = kstep * 32 + (lane >> 4) * 8 + j;
        int col = nt * 16 + (lane & 15);
        wbbf[i] = f2bf(Wbb[(size_t)f * 128 + col]);
    } else if (bid < 6400) {                // w2 -> w2f, 32768
        int i = (bid - 6272) * 256 + tid;
        int j = i & 7, lane = (i >> 3) & 63, kstep = (i >> 9) & 15, nt = i >> 13;
        int oc = nt * 16 + (lane & 15);
        int ic = 2 * kstep + (j >> 2);
        int ky = lane >> 4, kx = j & 3;
        w2f[i] = f2bf(w2[oc * 512 + ic * 16 + ky * 4 + kx]);
    } else if (bid < 6528) {                // gates -> wgf; m=2 holds Wta+Wtb, m=3 zero
        // k' relabeling (matches rnn packed-z layout): korig = kstep*32 + (j&1)*16 + g'*4 + (j>>1)
        int i = (bid - 6400) * 256 + tid;
        int j = i & 7, lane = (i >> 3) & 63, nt = (i >> 9) & 15, kstep = (i >> 13) & 3;
        int gq = (lane >> 4) & 3;
        int k = kstep * 32 + (j & 1) * 16 + gq * 4 + (j >> 1);
        int m = nt >> 2;
        int c = (nt & 3) * 16 + (lane & 15);
        float v;
        if (m == 0)      v = Wff1[k * 64 + c];
        else if (m == 1) v = Wff2[k * 64 + c];
        else if (m == 2) v = Wta[k * 64 + c] + Wtb[k * 64 + c];
        else             v = 0.f;
        wgf[i] = f2bf(v);
    } else if (bid < 6560) {                // Wh -> whf, 8192
        int i = (bid - 6528) * 256 + tid;
        int j = i & 7, lane = (i >> 3) & 63, nt = (i >> 9) & 7, kstep = (i >> 12) & 1;
        int k = kstep * 32 + ((lane >> 4) & 3) * 8 + j;
        int col = nt * 16 + (lane & 15);
        whf[i] = f2bf(Wbb[(size_t)(FEATN + k) * 128 + col]);
    } else {                                // w1 -> w1f, 2048
        int i = (bid - 6560) * 256 + tid;
        if (i >= 2048) return;
        int j = i & 7, lane = (i >> 3) & 63, nt = (i >> 9) & 1, kstep = (i >> 10) & 1;
        int oc = nt * 16 + (lane & 15);
        int ky = (lane >> 4) & 3, kx = j & 3;
        float v;
        if (kstep == 0) { int ic = j >> 2; v = w1[oc * 48 + ic * 16 + ky * 4 + kx]; }
        else            { v = (j >> 2) == 0 ? w1[oc * 48 + 32 + ky * 4 + kx] : 0.f; }
        w1f[i] = f2bf(v);
    }
}

// ---------------- fused conv1+conv2, bf16 MFMA, h1 lives only in LDS ----------------
__global__ __launch_bounds__(512) void fused_conv(const float* __restrict__ x,
                                                  const float* __restrict__ b1,
                                                  const unsigned short* __restrict__ w1f,
                                                  const float* __restrict__ b2,
                                                  const unsigned short* __restrict__ w2f,
                                                  unsigned short* __restrict__ featb) {
    __shared__ unsigned short h1s[32 * 2 * PLANEP];   // 61696 B
    int img = blockIdx.x;
    int tid = threadIdx.x;
    int lane = tid & 63, wid = tid >> 6;               // wid 0..7
    int rowl = lane & 15, g = lane >> 4;
    const float* xg = x + (size_t)img * 11532;

    // ---- Part A: conv1 -> h1s ----
    {
        short8 bfr[2][2];
        #pragma unroll
        for (int ks = 0; ks < 2; ++ks)
            #pragma unroll
            for (int nt = 0; nt < 2; ++nt)
                bfr[ks][nt] = *(const short8*)(w1f + (((ks * 2 + nt) * 64 + lane) << 3));
        float bias0 = b1[rowl], bias1 = b1[16 + rowl];

        #pragma unroll
        for (int i = 0; i < 8; ++i) {
            int mtile = wid + 8 * i;
            if (mtile >= 57) break;
            int m = mtile * 16 + rowl; if (m > 899) m = 899;
            int oy = m / 30, ox = m - oy * 30;
            int y = 2 * oy + g, x0 = 2 * ox;
            const float* xb = xg + y * 62 + x0;
            union { unsigned int u[4]; short8 s; } af0, af1;
            #pragma unroll
            for (int c = 0; c < 2; ++c) {
                float2 p0 = *(const float2*)(xb + c * 3844);
                float2 p1 = *(const float2*)(xb + c * 3844 + 2);
                af0.u[c * 2]     = pack2bf_rhu(p0.x, p0.y);
                af0.u[c * 2 + 1] = pack2bf_rhu(p1.x, p1.y);
            }
            {
                float2 q0 = *(const float2*)(xb + 7688);
                float2 q1 = *(const float2*)(xb + 7690);
                af1.u[0] = pack2bf_rhu(q0.x, q0.y);
                af1.u[1] = pack2bf_rhu(q1.x, q1.y);
                af1.u[2] = 0; af1.u[3] = 0;
            }
            f32x4 acc0 = (f32x4){0.f, 0.f, 0.f, 0.f};
            f32x4 acc1 = (f32x4){0.f, 0.f, 0.f, 0.f};
            acc0 = __builtin_amdgcn_mfma_f32_16x16x32_bf16(af0.s, bfr[0][0], acc0, 0, 0, 0);
            acc0 = __builtin_amdgcn_mfma_f32_16x16x32_bf16(af1.s, bfr[1][0], acc0, 0, 0, 0);
            acc1 = __builtin_amdgcn_mfma_f32_16x16x32_bf16(af0.s, bfr[0][1], acc1, 0, 0, 0);
            acc1 = __builtin_amdgcn_mfma_f32_16x16x32_bf16(af1.s, bfr[1][1], acc1, 0, 0, 0);
            // epilogue: bias+relu+bf16 -> h1s[oc][oy][ox]
            int sp0 = mtile * 16 + g * 4;
            int oy0 = sp0 / 30, ox0 = sp0 - oy0 * 30;
            #pragma unroll
            for (int nt = 0; nt < 2; ++nt) {
                f32x4 a = nt ? acc1 : acc0;
                int oc = nt * 16 + rowl;
                float bias = nt ? bias1 : bias0;
                int pbase = oc * (2 * PLANEP);
                #pragma unroll
                for (int r = 0; r < 4; ++r) {
                    if (sp0 + r > 899) break;
                    int oxr = ox0 + r, oyr = oy0;
                    if (oxr >= 30) { oxr -= 30; ++oyr; }
                    h1s[pbase + oyr * 32 + oxr] = f2bf_rhu(fmaxf(a[r] + bias, 0.f));
                }
            }
        }
    }
    __syncthreads();

    // ---- Part B: conv2 -> featb ----
    f32x4 acc[2][4];
    #pragma unroll
    for (int i = 0; i < 2; ++i)
        #pragma unroll
        for (int nt = 0; nt < 4; ++nt) acc[i][nt] = (f32x4){0.f, 0.f, 0.f, 0.f};

    int dofs[2];
    #pragma unroll
    for (int i = 0; i < 2; ++i) {
        int mtile = wid + 8 * i;
        int m = mtile * 16 + rowl; if (m > 195) m = 195;
        int oy = m / 14, ox = m - oy * 14;
        int y = 2 * oy + g, x0 = 2 * ox;
        dofs[i] = y * 16 + (x0 >> 1);
    }
    const unsigned int* lds32 = (const unsigned int*)h1s;

    #pragma unroll 4
    for (int kstep = 0; kstep < 16; ++kstep) {
        short8 bfr[4];
        #pragma unroll
        for (int nt = 0; nt < 4; ++nt)
            bfr[nt] = *(const short8*)(w2f + (((nt * 16 + kstep) * 64 + lane) << 3));
        int icb = kstep * 2 * PLANEP;
        #pragma unroll
        for (int i = 0; i < 2; ++i) {
            int mtile = wid + 8 * i;
            if (mtile < 13) {
                int dof = icb + dofs[i];
                union { unsigned int u[4]; short8 s; } af;
                af.u[0] = lds32[dof];
                af.u[1] = lds32[dof + 1];
                af.u[2] = lds32[dof + PLANEP];
                af.u[3] = lds32[dof + PLANEP + 1];
                #pragma unroll
                for (int nt = 0; nt < 4; ++nt)
                    acc[i][nt] = __builtin_amdgcn_mfma_f32_16x16x32_bf16(af.s, bfr[nt], acc[i][nt], 0, 0, 0);
            }
        }
    }
    #pragma unroll
    for (int i = 0; i < 2; ++i) {
        int mtile = wid + 8 * i;
        if (mtile >= 13) continue;
        int sp0 = mtile * 16 + g * 4;
        #pragma unroll
        for (int nt = 0; nt < 4; ++nt) {
            int oc = nt * 16 + rowl;
            float bias = b2[oc];
            unsigned short pk[4];
            #pragma unroll
            for (int r = 0; r < 4; ++r)
                pk[r] = f2bf_rhu(fmaxf(acc[i][nt][r] + bias, 0.f));
            unsigned short* dstp = featb + (size_t)img * 12544 + oc * 196 + sp0;
            if (sp0 + 3 < 196) {
                *(uint2*)dstp = *(uint2*)pk;
            } else {
                #pragma unroll
                for (int r = 0; r < 4; ++r) if (sp0 + r < 196) dstp[r] = pk[r];
            }
        }
    }
}

// ---------------- u = feat @ W_in : bf16 MFMA, split-K=28 (R14-measured config) ----------------
__global__ __launch_bounds__(256) void gemm_u_mfma(const unsigned short* __restrict__ featb,
                                                   const unsigned short* __restrict__ Wbbf,
                                                   float* __restrict__ part) {
    int tid = threadIdx.x, lane = tid & 63, wid = tid >> 6;
    int rowl = lane & 15, g = lane >> 4;
    int m0 = blockIdx.x * 64 + wid * 16;
    int ks0 = blockIdx.y * 14;
    f32x4 acc[8];
    #pragma unroll
    for (int nt = 0; nt < 8; ++nt) acc[nt] = (f32x4){0.f, 0.f, 0.f, 0.f};
    const unsigned short* arow = featb + (size_t)(m0 + rowl) * FEATN + g * 8;
    #pragma unroll 2
    for (int kk = 0; kk < 14; ++kk) {
        int kstep = ks0 + kk;
        short8 afr = *(const short8*)(arow + kstep * 32);
        #pragma unroll
        for (int nt = 0; nt < 8; ++nt) {
            short8 bfr = *(const short8*)(Wbbf + ((((size_t)kstep * 8 + nt) * 64 + lane) << 3));
            acc[nt] = __builtin_amdgcn_mfma_f32_16x16x32_bf16(afr, bfr, acc[nt], 0, 0, 0);
        }
    }
    float* pg = part + (size_t)blockIdx.y * 131072;
    #pragma unroll
    for (int nt = 0; nt < 8; ++nt)
        #pragma unroll
        for (int r = 0; r < 4; ++r)
            pg[(m0 + g * 4 + r) * 128 + nt * 16 + rowl] = acc[nt][r];
}

// reduce 28 splits; write u transposed to [t][c][b] (4 scalar stores)
__global__ void reduce_u(const float4* __restrict__ part4, const float* __restrict__ bbb,
                         float* __restrict__ u) {
    int o = blockIdx.x * 256 + threadIdx.x;   // 32768 float4s over c
    int c4 = o & 31, b = (o >> 5) & 15, t = o >> 9;
    int m = b * 64 + t;
    float4 s = *(const float4*)(bbb + c4 * 4);
    #pragma unroll
    for (int ks = 0; ks < 28; ++ks) {
        float4 p = part4[(size_t)ks * 32768 + m * 32 + c4];
        s.x += p.x; s.y += p.y; s.z += p.z; s.w += p.w;
    }
    int cb = c4 * 4;
    u[((size_t)t * 128 + cb + 0) * 16 + b] = s.x;
    u[((size_t)t * 128 + cb + 1) * 16 + b] = s.y;
    u[((size_t)t * 128 + cb + 2) * 16 + b] = s.z;
    u[((size_t)t * 128 + cb + 3) * 16 + b] = s.w;
}

// ---------------- liquid RNN scan + fused head: 1 block, 4 waves, single-bf16 state ----------------
__global__ __launch_bounds__(256, 1) void rnn_mfma(const float* __restrict__ u,
                                                   const unsigned short* __restrict__ whf,
                                                   const unsigned short* __restrict__ wgf,
                                                   const float* __restrict__ bff1,
                                                   const float* __restrict__ bff2,
                                                   const float* __restrict__ bta,
                                                   const float* __restrict__ btb,
                                                   const float* __restrict__ Wout,
                                                   const float* __restrict__ bout,
                                                   float* __restrict__ out) {
    __shared__ unsigned short hidA[16 * 64];    // [row][k0..63]
    __shared__ unsigned short zA[16 * 128];     // [row][k' 0..127] (reused as f32 hid for head)
    int tid = threadIdx.x, lane = tid & 63, w = tid >> 6;
    int rowl = lane & 15, g = lane >> 4;

    for (int idx = tid; idx < 1024; idx += 256) hidA[idx] = 0;

    // B-fragments -> registers (once)
    short8 wh_r[2][2];   // [kstep][ntl], nt_abs = 2w + ntl
    #pragma unroll
    for (int ks = 0; ks < 2; ++ks)
        #pragma unroll
        for (int ntl = 0; ntl < 2; ++ntl)
            wh_r[ks][ntl] = *(const short8*)(whf + (((ks * 8 + 2 * w + ntl) * 64 + lane) << 3));
    short8 wg_r[3][4];   // [m][kstep], nt_abs = 4m + w  (m=2 holds Wta+Wtb)
    #pragma unroll
    for (int m = 0; m < 3; ++m)
        #pragma unroll
        for (int ks = 0; ks < 4; ++ks)
            wg_r[m][ks] = *(const short8*)(wgf + (((ks * 16 + 4 * m + w) * 64 + lane) << 3));

    int cc = w * 16 + rowl;                   // this lane's phase-2 column
    float bias1 = bff1[cc], bias2 = bff2[cc], biast = bta[cc] + btb[cc];

    // u [t][c][b] pointers: 2 float4 loads per step (b = g*4..g*4+3)
    const float* ub0 = u + ((size_t)(2 * w) * 16 + rowl) * 16 + g * 4;        // c0 slice
    const float* ub1 = u + ((size_t)(2 * w + 1) * 16 + rowl) * 16 + g * 4;    // c1 slice
    f32x4 upf[2];
    {
        float4 v0 = *(const float4*)ub0;
        float4 v1 = *(const float4*)ub1;
        upf[0] = (f32x4){v0.x, v0.y, v0.z, v0.w};
        upf[1] = (f32x4){v1.x, v1.y, v1.z, v1.w};
    }
    __syncthreads();

    float hidv[4];
    #pragma unroll 1
    for (int t = 0; t < 64; ++t) {
        // ---- Phase 1: z = lecun_tanh(u_t + hid @ Wh) ----
        short8 ah[2];
        #pragma unroll
        for (int ks = 0; ks < 2; ++ks) {
            int byte = (rowl * 128 + ks * 64 + g * 16) ^ ((rowl & 7) << 4);
            ah[ks] = *(const short8*)((const char*)hidA + byte);
        }
        f32x4 zacc[2];
        #pragma unroll
        for (int ntl = 0; ntl < 2; ++ntl) {
            zacc[ntl] = upf[ntl];
            #pragma unroll
            for (int ks = 0; ks < 2; ++ks)
                zacc[ntl] = __builtin_amdgcn_mfma_f32_16x16x32_bf16(ah[ks], wh_r[ks][ntl], zacc[ntl], 0, 0, 0);
        }
        // prefetch u for t+1 (overlaps rest of step)
        if (t < 63) {
            float4 v0 = *(const float4*)(ub0 + (size_t)(t + 1) * 2048);
            float4 v1 = *(const float4*)(ub1 + (size_t)(t + 1) * 2048);
            upf[0] = (f32x4){v0.x, v0.y, v0.z, v0.w};
            upf[1] = (f32x4){v1.x, v1.y, v1.z, v1.w};
        }
        // tanh + packed z write: k' = w*32 + rowl*2 + ntl -> one b32 per row
        #pragma unroll
        for (int r = 0; r < 4; ++r) {
            float z0 = lecun_tanh_fast(zacc[0][r]);
            float z1 = lecun_tanh_fast(zacc[1][r]);
            int row = g * 4 + r;
            int byte = (row * 256 + w * 64 + rowl * 4) ^ ((row & 7) << 4);
            *(unsigned int*)((char*)zA + byte) = pack2bf_rhu(z0, z1);
        }
        __syncthreads();
        // ---- Phase 2: [ff1|ff2|t] = z @ Wg ----
        short8 zfr[4];
        #pragma unroll
        for (int ks = 0; ks < 4; ++ks) {
            int byte = (rowl * 256 + ks * 64 + g * 16) ^ ((rowl & 7) << 4);
            zfr[ks] = *(const short8*)((const char*)zA + byte);
        }
        f32x4 facc[3];
        facc[0] = (f32x4){bias1, bias1, bias1, bias1};
        facc[1] = (f32x4){bias2, bias2, bias2, bias2};
        facc[2] = (f32x4){biast, biast, biast, biast};
        #pragma unroll
        for (int m = 0; m < 3; ++m)
            #pragma unroll
            for (int ks = 0; ks < 4; ++ks)
                facc[m] = __builtin_amdgcn_mfma_f32_16x16x32_bf16(zfr[ks], wg_r[m][ks], facc[m], 0, 0, 0);
        // activations + hid write (bf16)
        #pragma unroll
        for (int r = 0; r < 4; ++r) {
            float ff1 = tanh_fast(facc[0][r]);
            float ff2 = tanh_fast(facc[1][r]);
            float tt  = sigmoid_fast(facc[2][r]);
            float hv  = ff1 + tt * (ff2 - ff1);
            hidv[r] = hv;
            int row = g * 4 + r;
            int byte = (row * 128 + cc * 2) ^ ((row & 7) << 4);
            *(unsigned short*)((char*)hidA + byte) = f2bf_rhu(hv);
        }
        __syncthreads();
    }

    // ---- fused head: out[b][a] = hid[b] . Wout[:,a] + bout[a] ----
    float* hf = (float*)zA;                    // 16*64 f32 = 4096 B
    #pragma unroll
    for (int r = 0; r < 4; ++r) hf[(g * 4 + r) * 64 + cc] = hidv[r];
    __syncthreads();
    if (tid < 128) {
        int b = tid >> 3, a = tid & 7;
        float s = bout[a];
        #pragma unroll
        for (int j = 0; j < 64; ++j) s += hf[b * 64 + j] * Wout[j * 8 + a];
        out[tid] = s;
    }
}

extern "C" void kernel_launch(void* const* d_in, const int* in_sizes, int n_in,
                              void* d_out, int out_size, void* d_ws, size_t ws_size,
                              hipStream_t stream) {
    const float* x    = (const float*)d_in[0];
    const float* w1   = (const float*)d_in[1];
    const float* b1   = (const float*)d_in[2];
    const float* w2   = (const float*)d_in[3];
    const float* b2   = (const float*)d_in[4];
    const float* Wbb  = (const float*)d_in[5];
    const float* bbb  = (const float*)d_in[6];
    const float* Wff1 = (const float*)d_in[7];
    const float* bff1 = (const float*)d_in[8];
    const float* Wff2 = (const float*)d_in[9];
    const float* bff2 = (const float*)d_in[10];
    const float* Wta  = (const float*)d_in[11];
    const float* bta  = (const float*)d_in[12];
    const float* Wtb  = (const float*)d_in[13];
    const float* btb  = (const float*)d_in[14];
    const float* Wout = (const float*)d_in[15];
    const float* bout = (const float*)d_in[16];

    if (ws_size < (size_t)WS_BYTES) return;

    char* wsb = (char*)d_ws;
    unsigned short* w1f   = (unsigned short*)(wsb + OFF_W1F);
    unsigned short* w2f   = (unsigned short*)(wsb + OFF_W2F);
    unsigned short* wbbf  = (unsigned short*)(wsb + OFF_WBBF);
    unsigned short* featb = (unsigned short*)(wsb + OFF_FEATB);
    float*          u     = (float*)(wsb + OFF_U);
    float*          part  = (float*)(wsb + OFF_PART);
    unsigned short* whf   = (unsigned short*)(wsb + OFF_WHF);
    unsigned short* wgf   = (unsigned short*)(wsb + OFF_WGF);

    prep_all<<<6568, 256, 0, stream>>>(w1, w2, Wbb, Wff1, Wff2, Wta, Wtb,
                                       w1f, w2f, wbbf, whf, wgf);
    fused_conv<<<1024, 512, 0, stream>>>(x, b1, w1f, b2, w2f, featb);
    gemm_u_mfma<<<dim3(16, 28), 256, 0, stream>>>(featb, wbbf, part);
    reduce_u<<<128, 256, 0, stream>>>((const float4*)part, bbb, u);
    rnn_mfma<<<1, 256, 0, stream>>>(u, whf, wgf, bff1, bff2, bta, btb, Wout, bout, (float*)d_out);
}